// Round 10
// baseline (186.429 us; speedup 1.0000x reference)
//
#include <hip/hip_runtime.h>
#include <math.h>

// buffer [8,64,5,64,64] fp32; Wq/Wk [8,64]; Wv/Wc [40,64]; W1 [64,40,1,1,7]; W2 [64,64,7,1,1]
// out [8,64,5,64,64] fp32

typedef __attribute__((ext_vector_type(8))) short bf16x8;
typedef __attribute__((ext_vector_type(4))) short bf16x4;
typedef __attribute__((ext_vector_type(4))) float fp32x4;
typedef __attribute__((ext_vector_type(8))) unsigned short u16x8;

// ---- workspace layout ----
// float offsets:
#define OFF_WP      0         // [og=4][c=64][l=24] proj weights fp32            (6144 f)
#define OFF_Z       29696     // [bu=8][cz=40][ar=5][h=64][w=64] fp32            (6553600 f) end 6583296
// ushort offsets (us = (unsigned short*)ws):
#define OFF_W1P_US  12288     // [wid=4][ks=9][lane=64][8] bf16 A-frag pack      (18432 us)
#define OFF_W2P_US  30720     // [wid=4][kd=7][kk=2][lane=64][8] bf16            (28672 us) end us 59392 = f 29696
#define OFF_QFH_US  13166592  // [site=512][m=320][8] bf16                       (1310720 us)
#define OFF_KFH_US  14477312  // [site][n=320][8] bf16                           (1310720 us)
#define OFF_VTH_US  15788032  // [site][j=48][n=320] bf16 (j=40 ones)            (7864320 us) end us 23652352
#define OFF_ZB16_US 23652352  // [bu][ar=5][h][w][ic=40] bf16 attn+Wc sum        (6553600 us) end us 30205952
// total ws use = 60.4 MB (workspace allocation ~268 MB per fill size)

__device__ inline unsigned short f2b(float f) {   // RNE fp32 -> bf16
    unsigned u = __builtin_bit_cast(unsigned, f);
    u = (u + 0x7fffu + ((u >> 16) & 1u)) >> 16;
    return (unsigned short)u;
}

// 16x16x16 bf16 MFMA (legacy K=16 shape, retained on gfx950).
#if __has_builtin(__builtin_amdgcn_mfma_f32_16x16x16bf16_1k)
#define MFMA16(a, b, c) __builtin_amdgcn_mfma_f32_16x16x16bf16_1k(a, b, c, 0, 0, 0)
#else
static __device__ inline fp32x4 mfma16_asm(bf16x4 a, bf16x4 b, fp32x4 c) {
    asm("v_mfma_f32_16x16x16_bf16 %0, %1, %2, %0" : "+v"(c) : "v"(a), "v"(b));
    return c;
}
#define MFMA16(a, b, c) mfma16_asm(a, b, c)
#endif

// ---------------- kernel 0: weight shuffles / MFMA A-fragment packing ----------------
__global__ void prep_weights(const float* __restrict__ Wq, const float* __restrict__ Wk,
                             const float* __restrict__ Wv, const float* __restrict__ Wc,
                             const float* __restrict__ W1, const float* __restrict__ W2,
                             float* __restrict__ ws) {
    int e = blockIdx.x * 256 + threadIdx.x;
    unsigned short* us = (unsigned short*)ws;
    if (e < 6144) {
        int og = e / 1536, r = e % 1536;
        int c = r / 24, l = r % 24;
        int o = og * 24 + l;
        float v;
        if (o < 8)       v = Wq[o * 64 + c];
        else if (o < 16) v = Wk[(o - 8) * 64 + c];
        else if (o < 56) v = Wv[(o - 16) * 64 + c];
        else             v = Wc[(o - 56) * 64 + c];
        ws[OFF_WP + e] = v;
    } else if (e < 6144 + 18432) {
        // conv1 A pack: k = kw*40 + ic (K=280 padded to 288)
        int t = e - 6144;
        int j = t & 7, lane = (t >> 3) & 63, ks = (t >> 9) % 9, wid = t / 4608;
        int oc = wid * 16 + (lane & 15);
        int k = ks * 32 + (lane >> 4) * 8 + j;
        float v = 0.f;
        if (k < 280) { int kw = k / 40, ic = k % 40; v = W1[oc * 280 + ic * 7 + kw]; }
        us[OFF_W1P_US + t] = f2b(v);
    } else if (e < 6144 + 18432 + 28672) {
        // conv2 A pack: k = kd*64 + ic (K=448 exact)
        int t = e - 6144 - 18432;
        int j = t & 7, lane = (t >> 3) & 63, kk = (t >> 9) & 1, kd = (t >> 10) % 7, wid = t / 7168;
        int oc = wid * 16 + (lane & 15);
        int ic = kk * 32 + (lane >> 4) * 8 + j;
        us[OFF_W2P_US + t] = f2b(W2[oc * 448 + ic * 7 + kd]);
    }
}

// ---------------- kernel A: q/k/v/c projections (fused og, LDS-staged x) ----------------
// grid 2560 = (bu,v,h); 256 thr = 4 waves, wave = og. x-slab [c=64][w=64] fp32 staged to
// LDS once (coalesced float4). readfirstlane(og) keeps weight reads scalar.
__global__ __launch_bounds__(256) void proj_kernel(const float* __restrict__ buf,
                                                   float* __restrict__ ws) {
    __shared__ alignas(16) float xs[64 * 64];   // 16 KB
    int b = blockIdx.x;
    int h = b & 63;
    int v = (b >> 6) % 5;
    int bu = b / 320;
    int tid = threadIdx.x, wid = tid >> 6, w = tid & 63;

    // stage x[c][w] for this (bu,v,h): rows are 256B segments 80KB apart
    const float* xbase = buf + ((bu * 64) * 5 + v) * 4096 + h * 64;
    for (int e = tid; e < 1024; e += 256) {
        int c = e >> 4, wq = e & 15;
        *(float4*)&xs[c * 64 + wq * 4] = *(const float4*)&xbase[c * 20480 + wq * 4];
    }
    __syncthreads();

    int og = __builtin_amdgcn_readfirstlane(wid);
    const float* wp = ws + OFF_WP + og * 1536;

    float acc[24];
    #pragma unroll
    for (int l = 0; l < 24; l++) acc[l] = 0.f;
    for (int c = 0; c < 64; c++) {
        float x = xs[c * 64 + w];
        const float* wr = wp + c * 24;
        #pragma unroll
        for (int l = 0; l < 24; l++) acc[l] += wr[l] * x;
    }

    int site = bu * 64 + h;
    int n = v * 64 + w;
    unsigned short* base = (unsigned short*)ws;
    unsigned short* qfh = base + OFF_QFH_US;
    unsigned short* kfh = base + OFF_KFH_US;
    unsigned short* vth = base + OFF_VTH_US;
    float* z = ws + OFF_Z;

    if (og == 0) {
        u16x8 qv, kv;
        #pragma unroll
        for (int l = 0; l < 8; l++) { qv[l] = f2b(acc[l]); kv[l] = f2b(acc[8 + l]); }
        *(u16x8*)&qfh[(site * 320 + n) * 8] = qv;
        *(u16x8*)&kfh[(site * 320 + n) * 8] = kv;
        #pragma unroll
        for (int l = 16; l < 24; l++) vth[(site * 48 + (l - 16)) * 320 + n] = f2b(acc[l]);
    } else if (og == 1) {
        #pragma unroll
        for (int l = 0; l < 24; l++) vth[(site * 48 + 8 + l) * 320 + n] = f2b(acc[l]);
    } else if (og == 2) {
        #pragma unroll
        for (int l = 0; l < 8; l++) vth[(site * 48 + 32 + l) * 320 + n] = f2b(acc[l]);
        #pragma unroll
        for (int l = 8; l < 24; l++) {
            int j2 = l - 8;
            int c8 = j2 / 5, ar = j2 % 5;
            z[((bu * 40 + c8 * 5 + v) * 5 + ar) * 4096 + h * 64 + w] = acc[l];
        }
    } else {
        #pragma unroll
        for (int l = 0; l < 24; l++) {
            int j2 = 16 + l;
            int c8 = j2 / 5, ar = j2 % 5;
            z[((bu * 40 + c8 * 5 + v) * 5 + ar) * 4096 + h * 64 + w] = acc[l];
        }
        #pragma unroll
        for (int j = 40; j < 48; j++)
            vth[(site * 48 + j) * 320 + n] = (j == 40) ? (unsigned short)0x3F80 : (unsigned short)0;
    }
}

// ---------------- kernel B: attention, register-resident P, m-chunk split ----------------
// Swapped-operand QK: sT = mfma(K, Q) puts P[m=col][n=nt*16+quad*4+r] lane-local, which IS the
// 16x16x16 fragment layout -> exp + bf16-pack feeds PV directly from registers. PV computed as
// mfma(A=V^T, B=P) so out[j=quad*4+r][m=col]. m-chunk split (grid 2560); z (Wc part) prefetched
// before QK (R7, -4.6us); K staged in LDS (R9).
// R10: the final sum zold + acc*inv is rounded to bf16 HERE and written to zb16 in conv12's
// exact stage layout [bu][ar][h][w][ic] -- kills the z fp32 round-trip (attn 26MB write +
// conv12 26MB read + 50 f2b/wave) . Bit-identical: conv1 input was f2b(z) of the same fp32 sum.
__global__ __launch_bounds__(256, 2) void attn_kernel(float* __restrict__ ws) {
    __shared__ alignas(16) short vt[48 * 328];
    __shared__ alignas(16) short kl[320 * 8];   // 5 KB

    int bid = blockIdx.x;
    int chunk = bid >> 9;        // 0..4
    int site = bid & 511;
    int bu = site >> 6, h = site & 63;
    int tid = threadIdx.x;
    int wid = tid >> 6, lane = tid & 63;
    int col = lane & 15, quad = lane >> 4;

    const unsigned short* base = (const unsigned short*)ws;
    const unsigned short* qfh = base + OFF_QFH_US + site * 320 * 8;
    const unsigned short* kfh = base + OFF_KFH_US + site * 320 * 8;
    const unsigned short* vsrc = base + OFF_VTH_US + site * 48 * 320;
    float* z = ws + OFF_Z;
    unsigned short* zb16 = (unsigned short*)ws + OFF_ZB16_US;

    for (int e = tid; e < 48 * 40; e += 256) {
        int row = e / 40, c8o = e % 40;
        *(u16x8*)&vt[row * 328 + c8o * 8] = *(const u16x8*)&vsrc[row * 320 + c8o * 8];
    }
    for (int e = tid; e < 320; e += 256)
        *(u16x8*)&kl[e * 8] = *(const u16x8*)&kfh[e * 8];
    __syncthreads();

    // z-read channel offsets: j = jt*16 + quad*4 + r -> (c8*25 + ar)*4096, c8=j/5, ar=j%5
    int off0[4], off1[4], off2[4];
    #pragma unroll
    for (int r = 0; r < 4; r++) {
        int j0 = quad * 4 + r, j1 = j0 + 16, j2 = j0 + 32;
        off0[r] = ((j0 / 5) * 25 + j0 % 5) * 4096;
        off1[r] = ((j1 / 5) * 25 + j1 % 5) * 4096;
        off2[r] = ((j2 / 5) * 25 + j2 % 5) * 4096;
    }

    int mt = chunk * 4 + wid;    // this wave's m-tile (0..19)
    int m0 = mt * 16;

    // z-prefetch (Wc part): addresses known now; loads drain while QK/softmax/PV runs
    int v_idx = m0 >> 6, w0 = m0 & 63;          // uniform per m-tile
    float* zb = z + (bu * 200 + v_idx * 5) * 4096 + h * 64 + w0 + col;
    float zold0[4], zold1[4], zold2[4];
    #pragma unroll
    for (int r = 0; r < 4; r++) {
        zold0[r] = zb[off0[r]];
        zold1[r] = zb[off1[r]];
        zold2[r] = (quad < 2) ? zb[off2[r]] : 0.f;
    }

    // Q^T as B operand: quad 0 holds ch 0..7 for column m = m0+col
    bf16x8 qa = (bf16x8)0;
    if (quad == 0) qa = *(const bf16x8*)&qfh[(m0 + col) * 8];

    fp32x4 acc0 = {0.f, 0.f, 0.f, 0.f}, acc1 = acc0, acc2 = acc0;

    for (int cc = 0; cc < 4; cc++) {
        fp32x4 sT[5];
        #pragma unroll
        for (int u = 0; u < 5; u++) {
            int nt = cc * 5 + u;
            // A operand: K rows n = nt*16+col from LDS; k>=8 slots are don't-care (qa==0 there)
            bf16x8 kb = *(const bf16x8*)&kl[(nt * 16 + col) * 8];
            sT[u] = __builtin_amdgcn_mfma_f32_16x16x32_bf16(
                kb, qa, (fp32x4){0.f, 0.f, 0.f, 0.f}, 0, 0, 0);
        }
        #pragma unroll
        for (int u = 0; u < 5; u++) {
            int nt = cc * 5 + u;
            bf16x4 pa;   // P[m=col][n = nt*16 + quad*4 + r] -> K=16 fragment
            #pragma unroll
            for (int r = 0; r < 4; r++) pa[r] = (short)f2b(__expf(sT[u][r]));
            const short* vb = &vt[nt * 16 + quad * 4];
            acc0 = MFMA16(*(const bf16x4*)&vb[(col) * 328],      pa, acc0);
            acc1 = MFMA16(*(const bf16x4*)&vb[(16 + col) * 328], pa, acc1);
            acc2 = MFMA16(*(const bf16x4*)&vb[(32 + col) * 328], pa, acc2);
        }
    }

    // rowsum L[m=col] sits at j=40 -> acc2[0] on quad==2 lanes
    float L = __shfl(acc2[0], 32 + col, 64);
    float inv = 1.f / L;

    // zb16[bu][ar][h][w2][ic]: ar = j%5, ic = (j/5)*5 + v_idx, w2 = w0 + col
    unsigned short* zsb = zb16 + bu * 819200 + h * 2560 + (w0 + col) * 40 + v_idx;
    #pragma unroll
    for (int r = 0; r < 4; r++) {
        int j0 = quad * 4 + r, j1 = j0 + 16, j2 = j0 + 32;
        zsb[(j0 % 5) * 163840 + (j0 / 5) * 5] = f2b(zold0[r] + acc0[r] * inv);
        zsb[(j1 % 5) * 163840 + (j1 / 5) * 5] = f2b(zold1[r] + acc1[r] * inv);
        if (quad < 2)
            zsb[(j2 % 5) * 163840 + (j2 / 5) * 5] = f2b(zold2[r] + acc2[r] * inv);
    }
}

// ---------------- kernel C: fused conv1 (1,1,7) + conv2 (7,1,1) + ReLU via bf16 MFMA ----------------
// grid 512 = (bu,h); 256 thr. Phase 1 (conv1): per-ar slab [wp=w+kw (72)][ic 40] bf16, double-
// buffered; conv1 bf16 results written straight to the ol slab. Phase 2 (conv2): reads ol.
// R10: stage reads pre-rounded zb16 (attn wrote conv-ready bf16) -> pure contiguous uint4 copy,
// no f2b, half the bytes. LDS 46080+11520 = 57.6 KB.
__global__ __launch_bounds__(256) void conv12_mfma(float* __restrict__ ws,
                                                   float* __restrict__ out) {
    __shared__ alignas(16) unsigned short ol[320 * 72];      // 46080 B
    __shared__ alignas(16) unsigned short zl2[2][72 * 40];   // 11520 B
    int b = blockIdx.x;
    int bu = b >> 6, h = b & 63;
    int tid = threadIdx.x, wid = tid >> 6, lane = tid & 63;
    int col = lane & 15, quad = lane >> 4;
    const unsigned short* zb16 = (const unsigned short*)ws + OFF_ZB16_US;

    const unsigned short* w1p = (const unsigned short*)ws + OFF_W1P_US;
    bf16x8 a1[9];
    #pragma unroll
    for (int ks = 0; ks < 9; ks++)
        a1[ks] = *(const bf16x8*)&w1p[((wid * 9 + ks) * 64 + lane) * 8];

    // stage one ar-slab: halo zeros wp in {0,1,2,67..71}; interior = contiguous copy of
    // zb16[bu][ar][h][w 64][ic 40] into zl2 rows 3..66
    #define STAGE_AR(ar_, bufi_)                                                          \
        {                                                                                 \
            unsigned short* zb_ = zl2[bufi_];                                             \
            if (tid < 160) {                                                              \
                int wpi = tid / 20, icd = tid % 20;                                       \
                int wp = wpi < 3 ? wpi : wpi + 64;                                        \
                ((unsigned*)zb_)[wp * 20 + icd] = 0u;                                     \
            }                                                                             \
            const uint4* src4 = (const uint4*)(zb16 + bu * 819200 + (ar_) * 163840 + h * 2560); \
            uint4* dst4 = (uint4*)(zb_ + 120);                                            \
            for (int e = tid; e < 320; e += 256) dst4[e] = src4[e];                       \
        }

    STAGE_AR(0, 0);
    __syncthreads();
    for (int ar = 0; ar < 5; ar++) {
        if (ar < 4) STAGE_AR(ar + 1, (ar + 1) & 1);   // prefetch into other buffer
        const unsigned short* zb = zl2[ar & 1];
        #pragma unroll
        for (int w4 = 0; w4 < 4; w4++) {
            int bb = (w4 * 16 + col) * 40;   // wp = w + kw, zl[wp] = z[wp-3]
            fp32x4 acc = {0.f, 0.f, 0.f, 0.f};
            #pragma unroll
            for (int ks = 0; ks < 9; ks++) {
                bf16x8 bf = *(const bf16x8*)&zb[bb + ks * 32 + quad * 8];
                acc = __builtin_amdgcn_mfma_f32_16x16x32_bf16(a1[ks], bf, acc, 0, 0, 0);
            }
            ushort4 o;
            o.x = f2b(fmaxf(acc[0], 0.f));
            o.y = f2b(fmaxf(acc[1], 0.f));
            o.z = f2b(fmaxf(acc[2], 0.f));
            o.w = f2b(fmaxf(acc[3], 0.f));
            *(ushort4*)&ol[(ar * 64 + w4 * 16 + col) * 72 + wid * 16 + quad * 4] = o;
        }
        __syncthreads();   // stage(ar+1) done; compute(ar) reads done before next overwrite
    }
    #undef STAGE_AR

    // ---- phase 2: conv2 over ar from ol ----
    const unsigned short* w2p = (const unsigned short*)ws + OFF_W2P_US;
    bf16x8 a2[7][2];
    #pragma unroll
    for (int kd = 0; kd < 7; kd++)
        #pragma unroll
        for (int kk = 0; kk < 2; kk++)
            a2[kd][kk] = *(const bf16x8*)&w2p[(((wid * 7 + kd) * 2 + kk) * 64 + lane) * 8];

    for (int nt = 0; nt < 20; nt++) {
        int ar = nt >> 2, wbase = (nt & 3) * 16;
        fp32x4 acc = {0.f, 0.f, 0.f, 0.f};
        #pragma unroll
        for (int kd = 0; kd < 7; kd++) {
            int arp = ar + kd - 3;
            if (arp >= 0 && arp < 5) {   // uniform per (nt,kd)
                int sb = (arp * 64 + wbase + col) * 72;
                #pragma unroll
                for (int kk = 0; kk < 2; kk++) {
                    bf16x8 bf = *(const bf16x8*)&ol[sb + kk * 32 + quad * 8];
                    acc = __builtin_amdgcn_mfma_f32_16x16x32_bf16(a2[kd][kk], bf, acc, 0, 0, 0);
                }
            }
        }
        int w = wbase + col;
        #pragma unroll
        for (int r = 0; r < 4; r++) {
            int oc = wid * 16 + quad * 4 + r;
            out[((bu * 64 + oc) * 5 + ar) * 4096 + h * 64 + w] = fmaxf(acc[r], 0.f);
        }
    }
}

extern "C" void kernel_launch(void* const* d_in, const int* in_sizes, int n_in,
                              void* d_out, int out_size, void* d_ws, size_t ws_size,
                              hipStream_t stream) {
    const float* buf = (const float*)d_in[0];
    const float* Wq  = (const float*)d_in[1];
    const float* Wk  = (const float*)d_in[2];
    const float* Wv  = (const float*)d_in[3];
    const float* Wc  = (const float*)d_in[4];
    const float* W1  = (const float*)d_in[5];
    const float* W2  = (const float*)d_in[6];
    float* ws  = (float*)d_ws;
    float* out = (float*)d_out;

    prep_weights<<<208, 256, 0, stream>>>(Wq, Wk, Wv, Wc, W1, W2, ws);
    proj_kernel<<<2560, 256, 0, stream>>>(buf, ws);
    attn_kernel<<<2560, 256, 0, stream>>>(ws);
    conv12_mfma<<<512, 256, 0, stream>>>(ws, out);
}

// Round 11
// 162.953 us; speedup vs baseline: 1.1441x; 1.1441x over previous
//
#include <hip/hip_runtime.h>
#include <math.h>

// buffer [8,64,5,64,64] fp32; Wq/Wk [8,64]; Wv/Wc [40,64]; W1 [64,40,1,1,7]; W2 [64,64,7,1,1]
// out [8,64,5,64,64] fp32

typedef __attribute__((ext_vector_type(8))) short bf16x8;
typedef __attribute__((ext_vector_type(4))) short bf16x4;
typedef __attribute__((ext_vector_type(4))) float fp32x4;
typedef __attribute__((ext_vector_type(8))) unsigned short u16x8;

// ---- workspace layout ----
// float offsets:
#define OFF_WP      0         // [og=4][c=64][l=24] proj weights fp32            (6144 f)
#define OFF_Z       29696     // [bu=8][cz=40][ar=5][h=64][w=64] fp32            (6553600 f) end 6583296
// ushort offsets (us = (unsigned short*)ws):
#define OFF_W1P_US  12288     // [wid=4][ks=9][lane=64][8] bf16 A-frag pack      (18432 us)
#define OFF_W2P_US  30720     // [wid=4][kd=7][kk=2][lane=64][8] bf16            (28672 us) end us 59392 = f 29696
#define OFF_QFH_US  13166592  // [site=512][m=320][8] bf16                       (1310720 us)
#define OFF_KFH_US  14477312  // [site][n=320][8] bf16                           (1310720 us)
#define OFF_VTH_US  15788032  // [site][j=48][n=320] bf16 (j=40 ones)            (7864320 us) end us 23652352
#define OFF_ZB16_US 23652352  // [bu][cz=40][ar=5][h][w] bf16 attn+Wc sum (z layout!) (6553600 us) end us 30205952
// total ws use = 60.4 MB

__device__ inline unsigned short f2b(float f) {   // RNE fp32 -> bf16
    unsigned u = __builtin_bit_cast(unsigned, f);
    u = (u + 0x7fffu + ((u >> 16) & 1u)) >> 16;
    return (unsigned short)u;
}

// 16x16x16 bf16 MFMA (legacy K=16 shape, retained on gfx950).
#if __has_builtin(__builtin_amdgcn_mfma_f32_16x16x16bf16_1k)
#define MFMA16(a, b, c) __builtin_amdgcn_mfma_f32_16x16x16bf16_1k(a, b, c, 0, 0, 0)
#else
static __device__ inline fp32x4 mfma16_asm(bf16x4 a, bf16x4 b, fp32x4 c) {
    asm("v_mfma_f32_16x16x16_bf16 %0, %1, %2, %0" : "+v"(c) : "v"(a), "v"(b));
    return c;
}
#define MFMA16(a, b, c) mfma16_asm(a, b, c)
#endif

// ---------------- kernel 0: weight shuffles / MFMA A-fragment packing ----------------
__global__ void prep_weights(const float* __restrict__ Wq, const float* __restrict__ Wk,
                             const float* __restrict__ Wv, const float* __restrict__ Wc,
                             const float* __restrict__ W1, const float* __restrict__ W2,
                             float* __restrict__ ws) {
    int e = blockIdx.x * 256 + threadIdx.x;
    unsigned short* us = (unsigned short*)ws;
    if (e < 6144) {
        int og = e / 1536, r = e % 1536;
        int c = r / 24, l = r % 24;
        int o = og * 24 + l;
        float v;
        if (o < 8)       v = Wq[o * 64 + c];
        else if (o < 16) v = Wk[(o - 8) * 64 + c];
        else if (o < 56) v = Wv[(o - 16) * 64 + c];
        else             v = Wc[(o - 56) * 64 + c];
        ws[OFF_WP + e] = v;
    } else if (e < 6144 + 18432) {
        // conv1 A pack: k = kw*40 + ic (K=280 padded to 288)
        int t = e - 6144;
        int j = t & 7, lane = (t >> 3) & 63, ks = (t >> 9) % 9, wid = t / 4608;
        int oc = wid * 16 + (lane & 15);
        int k = ks * 32 + (lane >> 4) * 8 + j;
        float v = 0.f;
        if (k < 280) { int kw = k / 40, ic = k % 40; v = W1[oc * 280 + ic * 7 + kw]; }
        us[OFF_W1P_US + t] = f2b(v);
    } else if (e < 6144 + 18432 + 28672) {
        // conv2 A pack: k = kd*64 + ic (K=448 exact)
        int t = e - 6144 - 18432;
        int j = t & 7, lane = (t >> 3) & 63, kk = (t >> 9) & 1, kd = (t >> 10) % 7, wid = t / 7168;
        int oc = wid * 16 + (lane & 15);
        int ic = kk * 32 + (lane >> 4) * 8 + j;
        us[OFF_W2P_US + t] = f2b(W2[oc * 448 + ic * 7 + kd]);
    }
}

// ---------------- kernel A: q/k/v/c projections (fused og, LDS-staged x) ----------------
// grid 2560 = (bu,v,h); 256 thr = 4 waves, wave = og. x-slab [c=64][w=64] fp32 staged to
// LDS once (coalesced float4). readfirstlane(og) keeps weight reads scalar.
__global__ __launch_bounds__(256) void proj_kernel(const float* __restrict__ buf,
                                                   float* __restrict__ ws) {
    __shared__ alignas(16) float xs[64 * 64];   // 16 KB
    int b = blockIdx.x;
    int h = b & 63;
    int v = (b >> 6) % 5;
    int bu = b / 320;
    int tid = threadIdx.x, wid = tid >> 6, w = tid & 63;

    // stage x[c][w] for this (bu,v,h): rows are 256B segments 80KB apart
    const float* xbase = buf + ((bu * 64) * 5 + v) * 4096 + h * 64;
    for (int e = tid; e < 1024; e += 256) {
        int c = e >> 4, wq = e & 15;
        *(float4*)&xs[c * 64 + wq * 4] = *(const float4*)&xbase[c * 20480 + wq * 4];
    }
    __syncthreads();

    int og = __builtin_amdgcn_readfirstlane(wid);
    const float* wp = ws + OFF_WP + og * 1536;

    float acc[24];
    #pragma unroll
    for (int l = 0; l < 24; l++) acc[l] = 0.f;
    for (int c = 0; c < 64; c++) {
        float x = xs[c * 64 + w];
        const float* wr = wp + c * 24;
        #pragma unroll
        for (int l = 0; l < 24; l++) acc[l] += wr[l] * x;
    }

    int site = bu * 64 + h;
    int n = v * 64 + w;
    unsigned short* base = (unsigned short*)ws;
    unsigned short* qfh = base + OFF_QFH_US;
    unsigned short* kfh = base + OFF_KFH_US;
    unsigned short* vth = base + OFF_VTH_US;
    float* z = ws + OFF_Z;

    if (og == 0) {
        u16x8 qv, kv;
        #pragma unroll
        for (int l = 0; l < 8; l++) { qv[l] = f2b(acc[l]); kv[l] = f2b(acc[8 + l]); }
        *(u16x8*)&qfh[(site * 320 + n) * 8] = qv;
        *(u16x8*)&kfh[(site * 320 + n) * 8] = kv;
        #pragma unroll
        for (int l = 16; l < 24; l++) vth[(site * 48 + (l - 16)) * 320 + n] = f2b(acc[l]);
    } else if (og == 1) {
        #pragma unroll
        for (int l = 0; l < 24; l++) vth[(site * 48 + 8 + l) * 320 + n] = f2b(acc[l]);
    } else if (og == 2) {
        #pragma unroll
        for (int l = 0; l < 8; l++) vth[(site * 48 + 32 + l) * 320 + n] = f2b(acc[l]);
        #pragma unroll
        for (int l = 8; l < 24; l++) {
            int j2 = l - 8;
            int c8 = j2 / 5, ar = j2 % 5;
            z[((bu * 40 + c8 * 5 + v) * 5 + ar) * 4096 + h * 64 + w] = acc[l];
        }
    } else {
        #pragma unroll
        for (int l = 0; l < 24; l++) {
            int j2 = 16 + l;
            int c8 = j2 / 5, ar = j2 % 5;
            z[((bu * 40 + c8 * 5 + v) * 5 + ar) * 4096 + h * 64 + w] = acc[l];
        }
        #pragma unroll
        for (int j = 40; j < 48; j++)
            vth[(site * 48 + j) * 320 + n] = (j == 40) ? (unsigned short)0x3F80 : (unsigned short)0;
    }
}

// ---------------- kernel B: attention, register-resident P, m-chunk split ----------------
// Swapped-operand QK: sT = mfma(K, Q) puts P[m=col][n=nt*16+quad*4+r] lane-local, which IS the
// 16x16x16 fragment layout -> exp + bf16-pack feeds PV directly from registers. PV computed as
// mfma(A=V^T, B=P) so out[j=quad*4+r][m=col]. m-chunk split (grid 2560); z (Wc part) prefetched
// before QK (R7); K staged in LDS (R9).
// R10 post-mortem: zb16 with ic innermost scattered the epilogue stores (80B lane stride, 64
// lines/instr, L2 RFO: FETCH +15MB, WRITE +12MB, attn 29->55us). R11: zb16 in the fp32-z layout
// [bu][cz][ar][h][w] -- identical offset math as the proven fp32 path (off0/1/2 reused), 16
// cols = 32B contiguous per quad, sibling waves complete the lines. Bit-identical.
__global__ __launch_bounds__(256, 2) void attn_kernel(float* __restrict__ ws) {
    __shared__ alignas(16) short vt[48 * 328];
    __shared__ alignas(16) short kl[320 * 8];   // 5 KB

    int bid = blockIdx.x;
    int chunk = bid >> 9;        // 0..4
    int site = bid & 511;
    int bu = site >> 6, h = site & 63;
    int tid = threadIdx.x;
    int wid = tid >> 6, lane = tid & 63;
    int col = lane & 15, quad = lane >> 4;

    const unsigned short* base = (const unsigned short*)ws;
    const unsigned short* qfh = base + OFF_QFH_US + site * 320 * 8;
    const unsigned short* kfh = base + OFF_KFH_US + site * 320 * 8;
    const unsigned short* vsrc = base + OFF_VTH_US + site * 48 * 320;
    float* z = ws + OFF_Z;
    unsigned short* zb16 = (unsigned short*)ws + OFF_ZB16_US;

    for (int e = tid; e < 48 * 40; e += 256) {
        int row = e / 40, c8o = e % 40;
        *(u16x8*)&vt[row * 328 + c8o * 8] = *(const u16x8*)&vsrc[row * 320 + c8o * 8];
    }
    for (int e = tid; e < 320; e += 256)
        *(u16x8*)&kl[e * 8] = *(const u16x8*)&kfh[e * 8];
    __syncthreads();

    // channel offsets: j = jt*16 + quad*4 + r -> (c8*25 + ar)*4096, c8=j/5, ar=j%5
    // (element-index offsets: valid for BOTH fp32 z reads and us zb16 writes)
    int off0[4], off1[4], off2[4];
    #pragma unroll
    for (int r = 0; r < 4; r++) {
        int j0 = quad * 4 + r, j1 = j0 + 16, j2 = j0 + 32;
        off0[r] = ((j0 / 5) * 25 + j0 % 5) * 4096;
        off1[r] = ((j1 / 5) * 25 + j1 % 5) * 4096;
        off2[r] = ((j2 / 5) * 25 + j2 % 5) * 4096;
    }

    int mt = chunk * 4 + wid;    // this wave's m-tile (0..19)
    int m0 = mt * 16;

    // z-prefetch (Wc part): addresses known now; loads drain while QK/softmax/PV runs
    int v_idx = m0 >> 6, w0 = m0 & 63;          // uniform per m-tile
    int sbase = (bu * 200 + v_idx * 5) * 4096 + h * 64 + w0 + col;
    float* zb = z + sbase;
    float zold0[4], zold1[4], zold2[4];
    #pragma unroll
    for (int r = 0; r < 4; r++) {
        zold0[r] = zb[off0[r]];
        zold1[r] = zb[off1[r]];
        zold2[r] = (quad < 2) ? zb[off2[r]] : 0.f;
    }

    // Q^T as B operand: quad 0 holds ch 0..7 for column m = m0+col
    bf16x8 qa = (bf16x8)0;
    if (quad == 0) qa = *(const bf16x8*)&qfh[(m0 + col) * 8];

    fp32x4 acc0 = {0.f, 0.f, 0.f, 0.f}, acc1 = acc0, acc2 = acc0;

    for (int cc = 0; cc < 4; cc++) {
        fp32x4 sT[5];
        #pragma unroll
        for (int u = 0; u < 5; u++) {
            int nt = cc * 5 + u;
            // A operand: K rows n = nt*16+col from LDS; k>=8 slots are don't-care (qa==0 there)
            bf16x8 kb = *(const bf16x8*)&kl[(nt * 16 + col) * 8];
            sT[u] = __builtin_amdgcn_mfma_f32_16x16x32_bf16(
                kb, qa, (fp32x4){0.f, 0.f, 0.f, 0.f}, 0, 0, 0);
        }
        #pragma unroll
        for (int u = 0; u < 5; u++) {
            int nt = cc * 5 + u;
            bf16x4 pa;   // P[m=col][n = nt*16 + quad*4 + r] -> K=16 fragment
            #pragma unroll
            for (int r = 0; r < 4; r++) pa[r] = (short)f2b(__expf(sT[u][r]));
            const short* vb = &vt[nt * 16 + quad * 4];
            acc0 = MFMA16(*(const bf16x4*)&vb[(col) * 328],      pa, acc0);
            acc1 = MFMA16(*(const bf16x4*)&vb[(16 + col) * 328], pa, acc1);
            acc2 = MFMA16(*(const bf16x4*)&vb[(32 + col) * 328], pa, acc2);
        }
    }

    // rowsum L[m=col] sits at j=40 -> acc2[0] on quad==2 lanes
    float L = __shfl(acc2[0], 32 + col, 64);
    float inv = 1.f / L;

    // write final bf16 sum to zb16 (same layout/offsets as z, us units)
    unsigned short* zsb = zb16 + sbase;
    #pragma unroll
    for (int r = 0; r < 4; r++) {
        zsb[off0[r]] = f2b(zold0[r] + acc0[r] * inv);
        zsb[off1[r]] = f2b(zold1[r] + acc1[r] * inv);
        if (quad < 2) zsb[off2[r]] = f2b(zold2[r] + acc2[r] * inv);   // j = 32+quad*4+r < 40
    }
}

// ---------------- kernel C: fused conv1 (1,1,7) + conv2 (7,1,1) + ReLU via bf16 MFMA ----------------
// grid 512 = (bu,h); 256 thr. Phase 1 (conv1): per-ar slab [wp=w+kw (72)][ic 40] bf16, double-
// buffered; conv1 bf16 results written straight to the ol slab. Phase 2 (conv2): reads ol.
// R11: stage reads pre-rounded zb16 (z layout, bf16): 4 coalesced 2B loads (128B/instr), no f2b,
// half the bytes of the fp32 path. LDS 46080+11520 = 57.6 KB.
__global__ __launch_bounds__(256) void conv12_mfma(float* __restrict__ ws,
                                                   float* __restrict__ out) {
    __shared__ alignas(16) unsigned short ol[320 * 72];      // 46080 B
    __shared__ alignas(16) unsigned short zl2[2][72 * 40];   // 11520 B
    int b = blockIdx.x;
    int bu = b >> 6, h = b & 63;
    int tid = threadIdx.x, wid = tid >> 6, lane = tid & 63;
    int col = lane & 15, quad = lane >> 4;
    const unsigned short* zb16 = (const unsigned short*)ws + OFF_ZB16_US;

    const unsigned short* w1p = (const unsigned short*)ws + OFF_W1P_US;
    bf16x8 a1[9];
    #pragma unroll
    for (int ks = 0; ks < 9; ks++)
        a1[ks] = *(const bf16x8*)&w1p[((wid * 9 + ks) * 64 + lane) * 8];

    // stage one ar-slab of zb16 into zl2[bufi]: halo zeros wp in {0,1,2,67..71}, interior wp=3+w
    // per-cz stride in us = 5*4096 = 20480
    #define STAGE_AR(ar_, bufi_)                                                          \
        {                                                                                 \
            unsigned short* zb_ = zl2[bufi_];                                             \
            if (tid < 160) {                                                              \
                int wpi = tid / 20, icd = tid % 20;                                       \
                int wp = wpi < 3 ? wpi : wpi + 64;                                        \
                ((unsigned*)zb_)[wp * 20 + icd] = 0u;                                     \
            }                                                                             \
            for (int icq = wid; icq < 10; icq += 4) {                                     \
                const unsigned short* src = zb16 + ((bu * 40 + icq * 4) * 5 + (ar_)) * 4096 + h * 64 + lane; \
                ushort4 v4;                                                               \
                v4.x = src[0];                                                            \
                v4.y = src[20480];                                                        \
                v4.z = src[40960];                                                        \
                v4.w = src[61440];                                                        \
                *(ushort4*)&zb_[(3 + lane) * 40 + icq * 4] = v4;                          \
            }                                                                             \
        }

    STAGE_AR(0, 0);
    __syncthreads();
    for (int ar = 0; ar < 5; ar++) {
        if (ar < 4) STAGE_AR(ar + 1, (ar + 1) & 1);   // prefetch into other buffer
        const unsigned short* zb = zl2[ar & 1];
        #pragma unroll
        for (int w4 = 0; w4 < 4; w4++) {
            int bb = (w4 * 16 + col) * 40;   // wp = w + kw, zl[wp] = z[wp-3]
            fp32x4 acc = {0.f, 0.f, 0.f, 0.f};
            #pragma unroll
            for (int ks = 0; ks < 9; ks++) {
                bf16x8 bf = *(const bf16x8*)&zb[bb + ks * 32 + quad * 8];
                acc = __builtin_amdgcn_mfma_f32_16x16x32_bf16(a1[ks], bf, acc, 0, 0, 0);
            }
            ushort4 o;
            o.x = f2b(fmaxf(acc[0], 0.f));
            o.y = f2b(fmaxf(acc[1], 0.f));
            o.z = f2b(fmaxf(acc[2], 0.f));
            o.w = f2b(fmaxf(acc[3], 0.f));
            *(ushort4*)&ol[(ar * 64 + w4 * 16 + col) * 72 + wid * 16 + quad * 4] = o;
        }
        __syncthreads();   // stage(ar+1) done; compute(ar) reads done before next overwrite
    }
    #undef STAGE_AR

    // ---- phase 2: conv2 over ar from ol ----
    const unsigned short* w2p = (const unsigned short*)ws + OFF_W2P_US;
    bf16x8 a2[7][2];
    #pragma unroll
    for (int kd = 0; kd < 7; kd++)
        #pragma unroll
        for (int kk = 0; kk < 2; kk++)
            a2[kd][kk] = *(const bf16x8*)&w2p[(((wid * 7 + kd) * 2 + kk) * 64 + lane) * 8];

    for (int nt = 0; nt < 20; nt++) {
        int ar = nt >> 2, wbase = (nt & 3) * 16;
        fp32x4 acc = {0.f, 0.f, 0.f, 0.f};
        #pragma unroll
        for (int kd = 0; kd < 7; kd++) {
            int arp = ar + kd - 3;
            if (arp >= 0 && arp < 5) {   // uniform per (nt,kd)
                int sb = (arp * 64 + wbase + col) * 72;
                #pragma unroll
                for (int kk = 0; kk < 2; kk++) {
                    bf16x8 bf = *(const bf16x8*)&ol[sb + kk * 32 + quad * 8];
                    acc = __builtin_amdgcn_mfma_f32_16x16x32_bf16(a2[kd][kk], bf, acc, 0, 0, 0);
                }
            }
        }
        int w = wbase + col;
        #pragma unroll
        for (int r = 0; r < 4; r++) {
            int oc = wid * 16 + quad * 4 + r;
            out[((bu * 64 + oc) * 5 + ar) * 4096 + h * 64 + w] = fmaxf(acc[r], 0.f);
        }
    }
}

extern "C" void kernel_launch(void* const* d_in, const int* in_sizes, int n_in,
                              void* d_out, int out_size, void* d_ws, size_t ws_size,
                              hipStream_t stream) {
    const float* buf = (const float*)d_in[0];
    const float* Wq  = (const float*)d_in[1];
    const float* Wk  = (const float*)d_in[2];
    const float* Wv  = (const float*)d_in[3];
    const float* Wc  = (const float*)d_in[4];
    const float* W1  = (const float*)d_in[5];
    const float* W2  = (const float*)d_in[6];
    float* ws  = (float*)d_ws;
    float* out = (float*)d_out;

    prep_weights<<<208, 256, 0, stream>>>(Wq, Wk, Wv, Wc, W1, W2, ws);
    proj_kernel<<<2560, 256, 0, stream>>>(buf, ws);
    attn_kernel<<<2560, 256, 0, stream>>>(ws);
    conv12_mfma<<<512, 256, 0, stream>>>(ws, out);
}

// Round 12
// 155.877 us; speedup vs baseline: 1.1960x; 1.0454x over previous
//
#include <hip/hip_runtime.h>
#include <math.h>

// buffer [8,64,5,64,64] fp32; Wq/Wk [8,64]; Wv/Wc [40,64]; W1 [64,40,1,1,7]; W2 [64,64,7,1,1]
// out [8,64,5,64,64] fp32

typedef __attribute__((ext_vector_type(8))) short bf16x8;
typedef __attribute__((ext_vector_type(4))) short bf16x4;
typedef __attribute__((ext_vector_type(4))) float fp32x4;
typedef __attribute__((ext_vector_type(8))) unsigned short u16x8;

// ---- workspace layout ----
// ushort offsets (us = (unsigned short*)ws):
#define OFF_WPJ_US  0         // [mt=6][kt=2][lane=64][8] proj W A-frag bf16     (6144 us)
#define OFF_W1P_US  12288     // [wid=4][ks=9][lane=64][8] bf16 A-frag pack      (18432 us)
#define OFF_W2P_US  30720     // [wid=4][kd=7][kk=2][lane=64][8] bf16            (28672 us) end us 59392 = f 29696
#define OFF_QFH_US  13166592  // [site=512][m=320][8] bf16                       (1310720 us)
#define OFF_KFH_US  14477312  // [site][n=320][8] bf16                           (1310720 us)
#define OFF_VTH_US  15788032  // [site][j=48][n=320] bf16 (j=40 ones)            (7864320 us) end us 23652352
#define OFF_ZB16_US 23652352  // [bu][cz=40][ar=5][h][w] bf16 attn+Wc sum (z layout) (6553600 us) end us 30205952
// float offsets:
#define OFF_Z       29696     // [bu=8][cz=40][ar=5][h=64][w=64] fp32            (6553600 f) end 6583296

__device__ inline unsigned short f2b(float f) {   // RNE fp32 -> bf16
    unsigned u = __builtin_bit_cast(unsigned, f);
    u = (u + 0x7fffu + ((u >> 16) & 1u)) >> 16;
    return (unsigned short)u;
}

// 16x16x16 bf16 MFMA (legacy K=16 shape, retained on gfx950).
#if __has_builtin(__builtin_amdgcn_mfma_f32_16x16x16bf16_1k)
#define MFMA16(a, b, c) __builtin_amdgcn_mfma_f32_16x16x16bf16_1k(a, b, c, 0, 0, 0)
#else
static __device__ inline fp32x4 mfma16_asm(bf16x4 a, bf16x4 b, fp32x4 c) {
    asm("v_mfma_f32_16x16x16_bf16 %0, %1, %2, %0" : "+v"(c) : "v"(a), "v"(b));
    return c;
}
#define MFMA16(a, b, c) mfma16_asm(a, b, c)
#endif

// ---------------- kernel 0: weight shuffles / MFMA A-fragment packing ----------------
__global__ void prep_weights(const float* __restrict__ Wq, const float* __restrict__ Wk,
                             const float* __restrict__ Wv, const float* __restrict__ Wc,
                             const float* __restrict__ W1, const float* __restrict__ W2,
                             float* __restrict__ ws) {
    int e = blockIdx.x * 256 + threadIdx.x;
    unsigned short* us = (unsigned short*)ws;
    if (e < 6144) {
        // proj A pack: Wall[96][64] = [Wq;Wk;Wv;Wc], m = mt*16+(lane&15), k = kt*32+quad*8+j
        int mt = e >> 10, kt = (e >> 9) & 1, lane = (e >> 3) & 63, j = e & 7;
        int m = mt * 16 + (lane & 15);
        int k = kt * 32 + ((lane >> 4) & 3) * 8 + j;
        float v;
        if (m < 8)       v = Wq[m * 64 + k];
        else if (m < 16) v = Wk[(m - 8) * 64 + k];
        else if (m < 56) v = Wv[(m - 16) * 64 + k];
        else             v = Wc[(m - 56) * 64 + k];
        us[OFF_WPJ_US + e] = f2b(v);
    } else if (e < 6144 + 18432) {
        // conv1 A pack: k = kw*40 + ic (K=280 padded to 288)
        int t = e - 6144;
        int j = t & 7, lane = (t >> 3) & 63, ks = (t >> 9) % 9, wid = t / 4608;
        int oc = wid * 16 + (lane & 15);
        int k = ks * 32 + (lane >> 4) * 8 + j;
        float v = 0.f;
        if (k < 280) { int kw = k / 40, ic = k % 40; v = W1[oc * 280 + ic * 7 + kw]; }
        us[OFF_W1P_US + t] = f2b(v);
    } else if (e < 6144 + 18432 + 28672) {
        // conv2 A pack: k = kd*64 + ic (K=448 exact)
        int t = e - 6144 - 18432;
        int j = t & 7, lane = (t >> 3) & 63, kk = (t >> 9) & 1, kd = (t >> 10) % 7, wid = t / 7168;
        int oc = wid * 16 + (lane & 15);
        int ic = kk * 32 + (lane >> 4) * 8 + j;
        us[OFF_W2P_US + t] = f2b(W2[oc * 448 + ic * 7 + kd]);
    }
}

// ---------------- kernel A: q/k/v/c projections via bf16 MFMA ----------------
// R12: proj was VALU-floor-bound (1536 scalar FMA/lane ~ 13us; pk-FMA null in R6 confirmed
// formulation limit). Now a 96x64 channel GEMM on MFMA: grid 2560 = (bu,v,h); 4 waves, wave
// owns 16 pixels (n0 = wid*16). A = W (6 m-tiles x 2 k-tiles, packed by prep with conv1's
// proven fragment scheme); B = x from LDS (fp32 stage as before, f2b per-lane into 2 frags);
// 12 MFMAs/wave replace 1536 VALU FMAs/lane. C/D: row(=channel)=quad*4+r, col(=pixel)=lane&15
// (same interpretation as conv1 epilogue). Numerics: W,x rounded to bf16 pre-product (~0.3-0.5%
// rel) -- same order as existing output bf16 rounding; threshold headroom 2.7x.
__global__ __launch_bounds__(256) void proj_kernel(const float* __restrict__ buf,
                                                   float* __restrict__ ws) {
    __shared__ alignas(16) float xs[64 * 64];   // 16 KB
    int b = blockIdx.x;
    int h = b & 63;
    int v = (b >> 6) % 5;
    int bu = b / 320;
    int tid = threadIdx.x, wid = tid >> 6, lane = tid & 63;
    int col = lane & 15, quad = lane >> 4;

    // stage x[c][w] for this (bu,v,h): rows are 256B segments 80KB apart
    const float* xbase = buf + ((bu * 64) * 5 + v) * 4096 + h * 64;
    for (int e = tid; e < 1024; e += 256) {
        int c = e >> 4, wq = e & 15;
        *(float4*)&xs[c * 64 + wq * 4] = *(const float4*)&xbase[c * 20480 + wq * 4];
    }

    // A fragments (independent of LDS -> overlap with stage)
    const unsigned short* wpj = (const unsigned short*)ws + OFF_WPJ_US;
    bf16x8 aw[6][2];
    #pragma unroll
    for (int mt = 0; mt < 6; mt++)
        #pragma unroll
        for (int kt = 0; kt < 2; kt++)
            aw[mt][kt] = *(const bf16x8*)&wpj[((mt * 2 + kt) * 64 + lane) * 8];

    __syncthreads();

    // B fragments: x[k][n], k = kt*32 + quad*8 + j, n = n0 + col
    int n0 = wid * 16;
    bf16x8 xb[2];
    #pragma unroll
    for (int kt = 0; kt < 2; kt++) {
        u16x8 t;
        #pragma unroll
        for (int j = 0; j < 8; j++)
            t[j] = f2b(xs[(kt * 32 + quad * 8 + j) * 64 + n0 + col]);
        xb[kt] = __builtin_bit_cast(bf16x8, t);
    }

    fp32x4 acc[6];
    #pragma unroll
    for (int mt = 0; mt < 6; mt++) acc[mt] = (fp32x4){0.f, 0.f, 0.f, 0.f};
    #pragma unroll
    for (int kt = 0; kt < 2; kt++)
        #pragma unroll
        for (int mt = 0; mt < 6; mt++)
            acc[mt] = __builtin_amdgcn_mfma_f32_16x16x32_bf16(aw[mt][kt], xb[kt], acc[mt], 0, 0, 0);

    // ---- epilogue scatter: channel m = mt*16 + quad*4 + r, pixel w = n0 + col ----
    int site = bu * 64 + h;
    int w = n0 + col;
    int n_flat = v * 64 + w;
    unsigned short* base = (unsigned short*)ws;
    unsigned short* qfh = base + OFF_QFH_US;
    unsigned short* kfh = base + OFF_KFH_US;
    unsigned short* vth = base + OFF_VTH_US;
    float* z = ws + OFF_Z;

    // mt0: ch 0-7 = q (quads 0,1), ch 8-15 = k (quads 2,3)
    {
        ushort4 o;
        o.x = f2b(acc[0][0]); o.y = f2b(acc[0][1]); o.z = f2b(acc[0][2]); o.w = f2b(acc[0][3]);
        if (quad < 2) *(ushort4*)&qfh[(site * 320 + n_flat) * 8 + quad * 4] = o;
        else          *(ushort4*)&kfh[(site * 320 + n_flat) * 8 + (quad - 2) * 4] = o;
    }
    // mt1,2: Wv rows 0-31 -> vth j 0-31
    #pragma unroll
    for (int r = 0; r < 4; r++) {
        vth[(site * 48 + quad * 4 + r) * 320 + n_flat]      = f2b(acc[1][r]);
        vth[(site * 48 + 16 + quad * 4 + r) * 320 + n_flat] = f2b(acc[2][r]);
    }
    // mt3: quads 0,1 -> Wv rows 32-39 (vth j 32-39); quads 2,3 -> Wc rows 0-7 (z)
    if (quad < 2) {
        #pragma unroll
        for (int r = 0; r < 4; r++)
            vth[(site * 48 + 32 + quad * 4 + r) * 320 + n_flat] = f2b(acc[3][r]);
    } else {
        #pragma unroll
        for (int r = 0; r < 4; r++) {
            int jc = (quad - 2) * 4 + r;
            z[((bu * 40 + (jc / 5) * 5 + v) * 5 + (jc % 5)) * 4096 + h * 64 + w] = acc[3][r];
        }
    }
    // mt4,5: Wc rows 8-39 -> z
    #pragma unroll
    for (int r = 0; r < 4; r++) {
        int jc4 = 8 + quad * 4 + r;
        z[((bu * 40 + (jc4 / 5) * 5 + v) * 5 + (jc4 % 5)) * 4096 + h * 64 + w] = acc[4][r];
        int jc5 = 24 + quad * 4 + r;
        z[((bu * 40 + (jc5 / 5) * 5 + v) * 5 + (jc5 % 5)) * 4096 + h * 64 + w] = acc[5][r];
    }
    // ones rows j=40..47 (softmax denominator trick), one wave covers all 64 pixels
    if (wid == 3) {
        #pragma unroll
        for (int j = 40; j < 48; j++)
            vth[(site * 48 + j) * 320 + v * 64 + lane] =
                (j == 40) ? (unsigned short)0x3F80 : (unsigned short)0;
    }
}

// ---------------- kernel B: attention, register-resident P, m-chunk split ----------------
// Swapped-operand QK: sT = mfma(K, Q) puts P[m=col][n=nt*16+quad*4+r] lane-local, which IS the
// 16x16x16 fragment layout -> exp + bf16-pack feeds PV directly from registers. PV computed as
// mfma(A=V^T, B=P) so out[j=quad*4+r][m=col]. m-chunk split (grid 2560); z (Wc part) prefetched
// before QK (R7); K staged in LDS (R9); final sum rounded to bf16 here into zb16 (z layout, R11).
__global__ __launch_bounds__(256, 2) void attn_kernel(float* __restrict__ ws) {
    __shared__ alignas(16) short vt[48 * 328];
    __shared__ alignas(16) short kl[320 * 8];   // 5 KB

    int bid = blockIdx.x;
    int chunk = bid >> 9;        // 0..4
    int site = bid & 511;
    int bu = site >> 6, h = site & 63;
    int tid = threadIdx.x;
    int wid = tid >> 6, lane = tid & 63;
    int col = lane & 15, quad = lane >> 4;

    const unsigned short* base = (const unsigned short*)ws;
    const unsigned short* qfh = base + OFF_QFH_US + site * 320 * 8;
    const unsigned short* kfh = base + OFF_KFH_US + site * 320 * 8;
    const unsigned short* vsrc = base + OFF_VTH_US + site * 48 * 320;
    float* z = ws + OFF_Z;
    unsigned short* zb16 = (unsigned short*)ws + OFF_ZB16_US;

    for (int e = tid; e < 48 * 40; e += 256) {
        int row = e / 40, c8o = e % 40;
        *(u16x8*)&vt[row * 328 + c8o * 8] = *(const u16x8*)&vsrc[row * 320 + c8o * 8];
    }
    for (int e = tid; e < 320; e += 256)
        *(u16x8*)&kl[e * 8] = *(const u16x8*)&kfh[e * 8];
    __syncthreads();

    // channel offsets: j = jt*16 + quad*4 + r -> (c8*25 + ar)*4096, c8=j/5, ar=j%5
    int off0[4], off1[4], off2[4];
    #pragma unroll
    for (int r = 0; r < 4; r++) {
        int j0 = quad * 4 + r, j1 = j0 + 16, j2 = j0 + 32;
        off0[r] = ((j0 / 5) * 25 + j0 % 5) * 4096;
        off1[r] = ((j1 / 5) * 25 + j1 % 5) * 4096;
        off2[r] = ((j2 / 5) * 25 + j2 % 5) * 4096;
    }

    int mt = chunk * 4 + wid;    // this wave's m-tile (0..19)
    int m0 = mt * 16;

    // z-prefetch (Wc part): addresses known now; loads drain while QK/softmax/PV runs
    int v_idx = m0 >> 6, w0 = m0 & 63;          // uniform per m-tile
    int sbase = (bu * 200 + v_idx * 5) * 4096 + h * 64 + w0 + col;
    float* zb = z + sbase;
    float zold0[4], zold1[4], zold2[4];
    #pragma unroll
    for (int r = 0; r < 4; r++) {
        zold0[r] = zb[off0[r]];
        zold1[r] = zb[off1[r]];
        zold2[r] = (quad < 2) ? zb[off2[r]] : 0.f;
    }

    // Q^T as B operand: quad 0 holds ch 0..7 for column m = m0+col
    bf16x8 qa = (bf16x8)0;
    if (quad == 0) qa = *(const bf16x8*)&qfh[(m0 + col) * 8];

    fp32x4 acc0 = {0.f, 0.f, 0.f, 0.f}, acc1 = acc0, acc2 = acc0;

    for (int cc = 0; cc < 4; cc++) {
        fp32x4 sT[5];
        #pragma unroll
        for (int u = 0; u < 5; u++) {
            int nt = cc * 5 + u;
            // A operand: K rows n = nt*16+col from LDS; k>=8 slots are don't-care (qa==0 there)
            bf16x8 kb = *(const bf16x8*)&kl[(nt * 16 + col) * 8];
            sT[u] = __builtin_amdgcn_mfma_f32_16x16x32_bf16(
                kb, qa, (fp32x4){0.f, 0.f, 0.f, 0.f}, 0, 0, 0);
        }
        #pragma unroll
        for (int u = 0; u < 5; u++) {
            int nt = cc * 5 + u;
            bf16x4 pa;   // P[m=col][n = nt*16 + quad*4 + r] -> K=16 fragment
            #pragma unroll
            for (int r = 0; r < 4; r++) pa[r] = (short)f2b(__expf(sT[u][r]));
            const short* vb = &vt[nt * 16 + quad * 4];
            acc0 = MFMA16(*(const bf16x4*)&vb[(col) * 328],      pa, acc0);
            acc1 = MFMA16(*(const bf16x4*)&vb[(16 + col) * 328], pa, acc1);
            acc2 = MFMA16(*(const bf16x4*)&vb[(32 + col) * 328], pa, acc2);
        }
    }

    // rowsum L[m=col] sits at j=40 -> acc2[0] on quad==2 lanes
    float L = __shfl(acc2[0], 32 + col, 64);
    float inv = 1.f / L;

    // write final bf16 sum to zb16 (same layout/offsets as z, us units)
    unsigned short* zsb = zb16 + sbase;
    #pragma unroll
    for (int r = 0; r < 4; r++) {
        zsb[off0[r]] = f2b(zold0[r] + acc0[r] * inv);
        zsb[off1[r]] = f2b(zold1[r] + acc1[r] * inv);
        if (quad < 2) zsb[off2[r]] = f2b(zold2[r] + acc2[r] * inv);   // j = 32+quad*4+r < 40
    }
}

// ---------------- kernel C: fused conv1 (1,1,7) + conv2 (7,1,1) + ReLU via bf16 MFMA ----------------
// grid 512 = (bu,h); 256 thr. Phase 1 (conv1): per-ar slab [wp=w+kw (72)][ic 40] bf16, double-
// buffered; conv1 bf16 results written straight to the ol slab. Phase 2 (conv2): reads ol.
// Stage reads pre-rounded zb16 (z layout, bf16): coalesced 2B loads, no f2b (R11).
__global__ __launch_bounds__(256) void conv12_mfma(float* __restrict__ ws,
                                                   float* __restrict__ out) {
    __shared__ alignas(16) unsigned short ol[320 * 72];      // 46080 B
    __shared__ alignas(16) unsigned short zl2[2][72 * 40];   // 11520 B
    int b = blockIdx.x;
    int bu = b >> 6, h = b & 63;
    int tid = threadIdx.x, wid = tid >> 6, lane = tid & 63;
    int col = lane & 15, quad = lane >> 4;
    const unsigned short* zb16 = (const unsigned short*)ws + OFF_ZB16_US;

    const unsigned short* w1p = (const unsigned short*)ws + OFF_W1P_US;
    bf16x8 a1[9];
    #pragma unroll
    for (int ks = 0; ks < 9; ks++)
        a1[ks] = *(const bf16x8*)&w1p[((wid * 9 + ks) * 64 + lane) * 8];

    // stage one ar-slab of zb16 into zl2[bufi]: halo zeros wp in {0,1,2,67..71}, interior wp=3+w
    // per-cz stride in us = 5*4096 = 20480
    #define STAGE_AR(ar_, bufi_)                                                          \
        {                                                                                 \
            unsigned short* zb_ = zl2[bufi_];                                             \
            if (tid < 160) {                                                              \
                int wpi = tid / 20, icd = tid % 20;                                       \
                int wp = wpi < 3 ? wpi : wpi + 64;                                        \
                ((unsigned*)zb_)[wp * 20 + icd] = 0u;                                     \
            }                                                                             \
            for (int icq = wid; icq < 10; icq += 4) {                                     \
                const unsigned short* src = zb16 + ((bu * 40 + icq * 4) * 5 + (ar_)) * 4096 + h * 64 + lane; \
                ushort4 v4;                                                               \
                v4.x = src[0];                                                            \
                v4.y = src[20480];                                                        \
                v4.z = src[40960];                                                        \
                v4.w = src[61440];                                                        \
                *(ushort4*)&zb_[(3 + lane) * 40 + icq * 4] = v4;                          \
            }                                                                             \
        }

    STAGE_AR(0, 0);
    __syncthreads();
    for (int ar = 0; ar < 5; ar++) {
        if (ar < 4) STAGE_AR(ar + 1, (ar + 1) & 1);   // prefetch into other buffer
        const unsigned short* zb = zl2[ar & 1];
        #pragma unroll
        for (int w4 = 0; w4 < 4; w4++) {
            int bb = (w4 * 16 + col) * 40;   // wp = w + kw, zl[wp] = z[wp-3]
            fp32x4 acc = {0.f, 0.f, 0.f, 0.f};
            #pragma unroll
            for (int ks = 0; ks < 9; ks++) {
                bf16x8 bf = *(const bf16x8*)&zb[bb + ks * 32 + quad * 8];
                acc = __builtin_amdgcn_mfma_f32_16x16x32_bf16(a1[ks], bf, acc, 0, 0, 0);
            }
            ushort4 o;
            o.x = f2b(fmaxf(acc[0], 0.f));
            o.y = f2b(fmaxf(acc[1], 0.f));
            o.z = f2b(fmaxf(acc[2], 0.f));
            o.w = f2b(fmaxf(acc[3], 0.f));
            *(ushort4*)&ol[(ar * 64 + w4 * 16 + col) * 72 + wid * 16 + quad * 4] = o;
        }
        __syncthreads();   // stage(ar+1) done; compute(ar) reads done before next overwrite
    }
    #undef STAGE_AR

    // ---- phase 2: conv2 over ar from ol ----
    const unsigned short* w2p = (const unsigned short*)ws + OFF_W2P_US;
    bf16x8 a2[7][2];
    #pragma unroll
    for (int kd = 0; kd < 7; kd++)
        #pragma unroll
        for (int kk = 0; kk < 2; kk++)
            a2[kd][kk] = *(const bf16x8*)&w2p[(((wid * 7 + kd) * 2 + kk) * 64 + lane) * 8];

    for (int nt = 0; nt < 20; nt++) {
        int ar = nt >> 2, wbase = (nt & 3) * 16;
        fp32x4 acc = {0.f, 0.f, 0.f, 0.f};
        #pragma unroll
        for (int kd = 0; kd < 7; kd++) {
            int arp = ar + kd - 3;
            if (arp >= 0 && arp < 5) {   // uniform per (nt,kd)
                int sb = (arp * 64 + wbase + col) * 72;
                #pragma unroll
                for (int kk = 0; kk < 2; kk++) {
                    bf16x8 bf = *(const bf16x8*)&ol[sb + kk * 32 + quad * 8];
                    acc = __builtin_amdgcn_mfma_f32_16x16x32_bf16(a2[kd][kk], bf, acc, 0, 0, 0);
                }
            }
        }
        int w = wbase + col;
        #pragma unroll
        for (int r = 0; r < 4; r++) {
            int oc = wid * 16 + quad * 4 + r;
            out[((bu * 64 + oc) * 5 + ar) * 4096 + h * 64 + w] = fmaxf(acc[r], 0.f);
        }
    }
}

extern "C" void kernel_launch(void* const* d_in, const int* in_sizes, int n_in,
                              void* d_out, int out_size, void* d_ws, size_t ws_size,
                              hipStream_t stream) {
    const float* buf = (const float*)d_in[0];
    const float* Wq  = (const float*)d_in[1];
    const float* Wk  = (const float*)d_in[2];
    const float* Wv  = (const float*)d_in[3];
    const float* Wc  = (const float*)d_in[4];
    const float* W1  = (const float*)d_in[5];
    const float* W2  = (const float*)d_in[6];
    float* ws  = (float*)d_ws;
    float* out = (float*)d_out;

    prep_weights<<<208, 256, 0, stream>>>(Wq, Wk, Wv, Wc, W1, W2, ws);
    proj_kernel<<<2560, 256, 0, stream>>>(buf, ws);
    attn_kernel<<<2560, 256, 0, stream>>>(ws);
    conv12_mfma<<<512, 256, 0, stream>>>(ws, out);
}

// Round 13
// 143.357 us; speedup vs baseline: 1.3005x; 1.0873x over previous
//
#include <hip/hip_runtime.h>
#include <math.h>

// buffer [8,64,5,64,64] fp32; Wq/Wk [8,64]; Wv/Wc [40,64]; W1 [64,40,1,1,7]; W2 [64,64,7,1,1]
// out [8,64,5,64,64] fp32

typedef __attribute__((ext_vector_type(8))) short bf16x8;
typedef __attribute__((ext_vector_type(4))) short bf16x4;
typedef __attribute__((ext_vector_type(4))) float fp32x4;
typedef __attribute__((ext_vector_type(8))) unsigned short u16x8;

// ---- workspace layout ----
// ushort offsets (us = (unsigned short*)ws):
#define OFF_WPJ_US  0         // [mt=6][kt=2][lane=64][8] proj W A-frag bf16     (6144 us)
#define OFF_W1P_US  12288     // [wid=4][ks=9][lane=64][8] bf16 A-frag pack      (18432 us)
#define OFF_W2P_US  30720     // [wid=4][kd=7][kk=2][lane=64][8] bf16            (28672 us) end us 59392 = f 29696
#define OFF_QFH_US  13166592  // [site=512][m=320][8] bf16                       (1310720 us)
#define OFF_KFH_US  14477312  // [site][n=320][8] bf16                           (1310720 us)
#define OFF_VTH_US  15788032  // [site][j=48][n=320] bf16 (j=40 ones)            (7864320 us) end us 23652352
#define OFF_ZB16_US 23652352  // [bu][cz=40][ar=5][h][w] bf16 attn+Wc sum (z layout) (6553600 us) end us 30205952
// float offsets:
#define OFF_Z       29696     // [bu=8][cz=40][ar=5][h=64][w=64] fp32            (6553600 f) end 6583296

__device__ inline unsigned short f2b(float f) {   // RNE fp32 -> bf16
    unsigned u = __builtin_bit_cast(unsigned, f);
    u = (u + 0x7fffu + ((u >> 16) & 1u)) >> 16;
    return (unsigned short)u;
}

// 16x16x16 bf16 MFMA (legacy K=16 shape, retained on gfx950).
#if __has_builtin(__builtin_amdgcn_mfma_f32_16x16x16bf16_1k)
#define MFMA16(a, b, c) __builtin_amdgcn_mfma_f32_16x16x16bf16_1k(a, b, c, 0, 0, 0)
#else
static __device__ inline fp32x4 mfma16_asm(bf16x4 a, bf16x4 b, fp32x4 c) {
    asm("v_mfma_f32_16x16x16_bf16 %0, %1, %2, %0" : "+v"(c) : "v"(a), "v"(b));
    return c;
}
#define MFMA16(a, b, c) mfma16_asm(a, b, c)
#endif

// ---------------- kernel 0: weight shuffles / MFMA A-fragment packing ----------------
__global__ void prep_weights(const float* __restrict__ Wq, const float* __restrict__ Wk,
                             const float* __restrict__ Wv, const float* __restrict__ Wc,
                             const float* __restrict__ W1, const float* __restrict__ W2,
                             float* __restrict__ ws) {
    int e = blockIdx.x * 256 + threadIdx.x;
    unsigned short* us = (unsigned short*)ws;
    if (e < 6144) {
        // proj A pack: Wall[96][64] = [Wq;Wk;Wv;Wc], m = mt*16+(lane&15), k = kt*32+quad*8+j
        int mt = e >> 10, kt = (e >> 9) & 1, lane = (e >> 3) & 63, j = e & 7;
        int m = mt * 16 + (lane & 15);
        int k = kt * 32 + ((lane >> 4) & 3) * 8 + j;
        float v;
        if (m < 8)       v = Wq[m * 64 + k];
        else if (m < 16) v = Wk[(m - 8) * 64 + k];
        else if (m < 56) v = Wv[(m - 16) * 64 + k];
        else             v = Wc[(m - 56) * 64 + k];
        us[OFF_WPJ_US + e] = f2b(v);
    } else if (e < 6144 + 18432) {
        // conv1 A pack: k = kw*40 + ic (K=280 padded to 288)
        int t = e - 6144;
        int j = t & 7, lane = (t >> 3) & 63, ks = (t >> 9) % 9, wid = t / 4608;
        int oc = wid * 16 + (lane & 15);
        int k = ks * 32 + (lane >> 4) * 8 + j;
        float v = 0.f;
        if (k < 280) { int kw = k / 40, ic = k % 40; v = W1[oc * 280 + ic * 7 + kw]; }
        us[OFF_W1P_US + t] = f2b(v);
    } else if (e < 6144 + 18432 + 28672) {
        // conv2 A pack: k = kd*64 + ic (K=448 exact)
        int t = e - 6144 - 18432;
        int j = t & 7, lane = (t >> 3) & 63, kk = (t >> 9) & 1, kd = (t >> 10) % 7, wid = t / 7168;
        int oc = wid * 16 + (lane & 15);
        int ic = kk * 32 + (lane >> 4) * 8 + j;
        us[OFF_W2P_US + t] = f2b(W2[oc * 448 + ic * 7 + kd]);
    }
}

// ---------------- kernel A: q/k/v/c projections via bf16 MFMA (R12) ----------------
// grid 2560 = (bu,v,h); 4 waves, wave owns 16 pixels. A = W (6 m-tiles x 2 k-tiles), B = x
// from LDS (f2b per lane). 12 MFMAs replace 1536 VALU FMAs/lane.
__global__ __launch_bounds__(256) void proj_kernel(const float* __restrict__ buf,
                                                   float* __restrict__ ws) {
    __shared__ alignas(16) float xs[64 * 64];   // 16 KB
    int b = blockIdx.x;
    int h = b & 63;
    int v = (b >> 6) % 5;
    int bu = b / 320;
    int tid = threadIdx.x, wid = tid >> 6, lane = tid & 63;
    int col = lane & 15, quad = lane >> 4;

    const float* xbase = buf + ((bu * 64) * 5 + v) * 4096 + h * 64;
    for (int e = tid; e < 1024; e += 256) {
        int c = e >> 4, wq = e & 15;
        *(float4*)&xs[c * 64 + wq * 4] = *(const float4*)&xbase[c * 20480 + wq * 4];
    }

    const unsigned short* wpj = (const unsigned short*)ws + OFF_WPJ_US;
    bf16x8 aw[6][2];
    #pragma unroll
    for (int mt = 0; mt < 6; mt++)
        #pragma unroll
        for (int kt = 0; kt < 2; kt++)
            aw[mt][kt] = *(const bf16x8*)&wpj[((mt * 2 + kt) * 64 + lane) * 8];

    __syncthreads();

    int n0 = wid * 16;
    bf16x8 xb[2];
    #pragma unroll
    for (int kt = 0; kt < 2; kt++) {
        u16x8 t;
        #pragma unroll
        for (int j = 0; j < 8; j++)
            t[j] = f2b(xs[(kt * 32 + quad * 8 + j) * 64 + n0 + col]);
        xb[kt] = __builtin_bit_cast(bf16x8, t);
    }

    fp32x4 acc[6];
    #pragma unroll
    for (int mt = 0; mt < 6; mt++) acc[mt] = (fp32x4){0.f, 0.f, 0.f, 0.f};
    #pragma unroll
    for (int kt = 0; kt < 2; kt++)
        #pragma unroll
        for (int mt = 0; mt < 6; mt++)
            acc[mt] = __builtin_amdgcn_mfma_f32_16x16x32_bf16(aw[mt][kt], xb[kt], acc[mt], 0, 0, 0);

    int site = bu * 64 + h;
    int w = n0 + col;
    int n_flat = v * 64 + w;
    unsigned short* base = (unsigned short*)ws;
    unsigned short* qfh = base + OFF_QFH_US;
    unsigned short* kfh = base + OFF_KFH_US;
    unsigned short* vth = base + OFF_VTH_US;
    float* z = ws + OFF_Z;

    {
        ushort4 o;
        o.x = f2b(acc[0][0]); o.y = f2b(acc[0][1]); o.z = f2b(acc[0][2]); o.w = f2b(acc[0][3]);
        if (quad < 2) *(ushort4*)&qfh[(site * 320 + n_flat) * 8 + quad * 4] = o;
        else          *(ushort4*)&kfh[(site * 320 + n_flat) * 8 + (quad - 2) * 4] = o;
    }
    #pragma unroll
    for (int r = 0; r < 4; r++) {
        vth[(site * 48 + quad * 4 + r) * 320 + n_flat]      = f2b(acc[1][r]);
        vth[(site * 48 + 16 + quad * 4 + r) * 320 + n_flat] = f2b(acc[2][r]);
    }
    if (quad < 2) {
        #pragma unroll
        for (int r = 0; r < 4; r++)
            vth[(site * 48 + 32 + quad * 4 + r) * 320 + n_flat] = f2b(acc[3][r]);
    } else {
        #pragma unroll
        for (int r = 0; r < 4; r++) {
            int jc = (quad - 2) * 4 + r;
            z[((bu * 40 + (jc / 5) * 5 + v) * 5 + (jc % 5)) * 4096 + h * 64 + w] = acc[3][r];
        }
    }
    #pragma unroll
    for (int r = 0; r < 4; r++) {
        int jc4 = 8 + quad * 4 + r;
        z[((bu * 40 + (jc4 / 5) * 5 + v) * 5 + (jc4 % 5)) * 4096 + h * 64 + w] = acc[4][r];
        int jc5 = 24 + quad * 4 + r;
        z[((bu * 40 + (jc5 / 5) * 5 + v) * 5 + (jc5 % 5)) * 4096 + h * 64 + w] = acc[5][r];
    }
    if (wid == 3) {
        #pragma unroll
        for (int j = 40; j < 48; j++)
            vth[(site * 48 + j) * 320 + v * 64 + lane] =
                (j == 40) ? (unsigned short)0x3F80 : (unsigned short)0;
    }
}

// ---------------- kernel B: fused attention + conv1 + conv2 ----------------
// R13: block = site (bu,h), 512 thr = 8 waves, grid 512 (= 2 blocks/CU by LDS 57.6KB).
// Phase A (attn, bodies unchanged from R12): 8 waves cover the 20 m-tiles in rounds 8+8+4;
// final bf16 sums -> zb16 (global, z layout). __syncthreads() drains vmcnt -> same-CU reads
// of zb16 are L1/L2-hot. Phase B (conv12, bodies unchanged): 8 waves, wave = (half = wid>>2,
// oc group g = wid&3); conv1 splits w4 by half, conv2 splits nt by half. LDS time-multiplexed:
// phase A vt(31.5K)+kl(5K) ends before phase B ol(46K)+zl2(11.5K) begins (barriers guard the
// aliasing). Kills the conv12 launch + makes attn phase 16 waves/CU (was ~10.5), conv 16 (was 8).
__global__ __launch_bounds__(512, 2) void attn_conv(float* __restrict__ ws,
                                                    float* __restrict__ out) {
    __shared__ alignas(16) unsigned char smem[57600];
    short* vt = (short*)smem;                                  // [48][328] sh, 31488 B
    short* kl = (short*)(smem + 31488);                        // [320][8] sh, 5120 B (ends 36608)

    int site = blockIdx.x;
    int bu = site >> 6, h = site & 63;
    int tid = threadIdx.x;
    int wid = tid >> 6, lane = tid & 63;
    int col = lane & 15, quad = lane >> 4;

    const unsigned short* base = (const unsigned short*)ws;
    const unsigned short* qfh = base + OFF_QFH_US + site * 320 * 8;
    const unsigned short* kfh = base + OFF_KFH_US + site * 320 * 8;
    const unsigned short* vsrc = base + OFF_VTH_US + site * 48 * 320;
    float* z = ws + OFF_Z;
    unsigned short* zb16 = (unsigned short*)ws + OFF_ZB16_US;

    // ---- phase A stage ----
    for (int e = tid; e < 48 * 40; e += 512) {
        int row = e / 40, c8o = e % 40;
        *(u16x8*)&vt[row * 328 + c8o * 8] = *(const u16x8*)&vsrc[row * 320 + c8o * 8];
    }
    for (int e = tid; e < 320; e += 512)
        *(u16x8*)&kl[e * 8] = *(const u16x8*)&kfh[e * 8];
    __syncthreads();

    // channel offsets: j = jt*16 + quad*4 + r -> (c8*25 + ar)*4096
    int off0[4], off1[4], off2[4];
    #pragma unroll
    for (int r = 0; r < 4; r++) {
        int j0 = quad * 4 + r, j1 = j0 + 16, j2 = j0 + 32;
        off0[r] = ((j0 / 5) * 25 + j0 % 5) * 4096;
        off1[r] = ((j1 / 5) * 25 + j1 % 5) * 4096;
        off2[r] = ((j2 / 5) * 25 + j2 % 5) * 4096;
    }

    // ---- phase A: attn, m-tiles in rounds (8,8,4) ----
    for (int round = 0; round < 3; round++) {
        int mt = round * 8 + wid;          // wave-uniform
        if (mt >= 20) break;
        int m0 = mt * 16;

        int v_idx = m0 >> 6, w0 = m0 & 63;
        int sbase = (bu * 200 + v_idx * 5) * 4096 + h * 64 + w0 + col;
        float* zb = z + sbase;
        float zold0[4], zold1[4], zold2[4];
        #pragma unroll
        for (int r = 0; r < 4; r++) {
            zold0[r] = zb[off0[r]];
            zold1[r] = zb[off1[r]];
            zold2[r] = (quad < 2) ? zb[off2[r]] : 0.f;
        }

        bf16x8 qa = (bf16x8)0;
        if (quad == 0) qa = *(const bf16x8*)&qfh[(m0 + col) * 8];

        fp32x4 acc0 = {0.f, 0.f, 0.f, 0.f}, acc1 = acc0, acc2 = acc0;

        for (int cc = 0; cc < 4; cc++) {
            fp32x4 sT[5];
            #pragma unroll
            for (int u = 0; u < 5; u++) {
                int nt = cc * 5 + u;
                bf16x8 kb = *(const bf16x8*)&kl[(nt * 16 + col) * 8];
                sT[u] = __builtin_amdgcn_mfma_f32_16x16x32_bf16(
                    kb, qa, (fp32x4){0.f, 0.f, 0.f, 0.f}, 0, 0, 0);
            }
            #pragma unroll
            for (int u = 0; u < 5; u++) {
                int nt = cc * 5 + u;
                bf16x4 pa;
                #pragma unroll
                for (int r = 0; r < 4; r++) pa[r] = (short)f2b(__expf(sT[u][r]));
                const short* vb = &vt[nt * 16 + quad * 4];
                acc0 = MFMA16(*(const bf16x4*)&vb[(col) * 328],      pa, acc0);
                acc1 = MFMA16(*(const bf16x4*)&vb[(16 + col) * 328], pa, acc1);
                acc2 = MFMA16(*(const bf16x4*)&vb[(32 + col) * 328], pa, acc2);
            }
        }

        float L = __shfl(acc2[0], 32 + col, 64);
        float inv = 1.f / L;

        unsigned short* zsb = zb16 + sbase;
        #pragma unroll
        for (int r = 0; r < 4; r++) {
            zsb[off0[r]] = f2b(zold0[r] + acc0[r] * inv);
            zsb[off1[r]] = f2b(zold1[r] + acc1[r] * inv);
            if (quad < 2) zsb[off2[r]] = f2b(zold2[r] + acc2[r] * inv);
        }
    }
    __syncthreads();   // drains vmcnt: zb16 visible; vt/kl reads done -> smem reusable

    // ---- phase B: conv1 (1,1,7) + conv2 (7,1,1) + ReLU ----
    unsigned short* ol = (unsigned short*)smem;                // [320][72] sh, 46080 B
    unsigned short* zl2 = (unsigned short*)(smem + 46080);     // [2][72*40] sh, 11520 B
    int g = wid & 3, half = wid >> 2;

    const unsigned short* w1p = (const unsigned short*)ws + OFF_W1P_US;
    bf16x8 a1[9];
    #pragma unroll
    for (int ks = 0; ks < 9; ks++)
        a1[ks] = *(const bf16x8*)&w1p[((g * 9 + ks) * 64 + lane) * 8];

    #define STAGE_AR(ar_, bufi_)                                                          \
        {                                                                                 \
            unsigned short* zb_ = zl2 + (bufi_) * 2880;                                   \
            if (tid < 160) {                                                              \
                int wpi = tid / 20, icd = tid % 20;                                       \
                int wp = wpi < 3 ? wpi : wpi + 64;                                        \
                ((unsigned*)zb_)[wp * 20 + icd] = 0u;                                     \
            }                                                                             \
            for (int icq = wid; icq < 10; icq += 8) {                                     \
                const unsigned short* src = zb16 + ((bu * 40 + icq * 4) * 5 + (ar_)) * 4096 + h * 64 + lane; \
                ushort4 v4;                                                               \
                v4.x = src[0];                                                            \
                v4.y = src[20480];                                                        \
                v4.z = src[40960];                                                        \
                v4.w = src[61440];                                                        \
                *(ushort4*)&zb_[(3 + lane) * 40 + icq * 4] = v4;                          \
            }                                                                             \
        }

    STAGE_AR(0, 0);
    __syncthreads();
    for (int ar = 0; ar < 5; ar++) {
        if (ar < 4) STAGE_AR(ar + 1, (ar + 1) & 1);
        const unsigned short* zbl = zl2 + (ar & 1) * 2880;
        #pragma unroll
        for (int w4h = 0; w4h < 2; w4h++) {
            int w4 = half * 2 + w4h;
            int bb = (w4 * 16 + col) * 40;
            fp32x4 acc = {0.f, 0.f, 0.f, 0.f};
            #pragma unroll
            for (int ks = 0; ks < 9; ks++) {
                bf16x8 bf = *(const bf16x8*)&zbl[bb + ks * 32 + quad * 8];
                acc = __builtin_amdgcn_mfma_f32_16x16x32_bf16(a1[ks], bf, acc, 0, 0, 0);
            }
            ushort4 o;
            o.x = f2b(fmaxf(acc[0], 0.f));
            o.y = f2b(fmaxf(acc[1], 0.f));
            o.z = f2b(fmaxf(acc[2], 0.f));
            o.w = f2b(fmaxf(acc[3], 0.f));
            *(ushort4*)&ol[(ar * 64 + w4 * 16 + col) * 72 + g * 16 + quad * 4] = o;
        }
        __syncthreads();
    }
    #undef STAGE_AR

    const unsigned short* w2p = (const unsigned short*)ws + OFF_W2P_US;
    bf16x8 a2[7][2];
    #pragma unroll
    for (int kd = 0; kd < 7; kd++)
        #pragma unroll
        for (int kk = 0; kk < 2; kk++)
            a2[kd][kk] = *(const bf16x8*)&w2p[(((g * 7 + kd) * 2 + kk) * 64 + lane) * 8];

    for (int i = 0; i < 10; i++) {
        int nt = half * 10 + i;
        int ar = nt >> 2, wbase = (nt & 3) * 16;
        fp32x4 acc = {0.f, 0.f, 0.f, 0.f};
        #pragma unroll
        for (int kd = 0; kd < 7; kd++) {
            int arp = ar + kd - 3;
            if (arp >= 0 && arp < 5) {
                int sb = (arp * 64 + wbase + col) * 72;
                #pragma unroll
                for (int kk = 0; kk < 2; kk++) {
                    bf16x8 bf = *(const bf16x8*)&ol[sb + kk * 32 + quad * 8];
                    acc = __builtin_amdgcn_mfma_f32_16x16x32_bf16(a2[kd][kk], bf, acc, 0, 0, 0);
                }
            }
        }
        int w = wbase + col;
        #pragma unroll
        for (int r = 0; r < 4; r++) {
            int oc = g * 16 + quad * 4 + r;
            out[((bu * 64 + oc) * 5 + ar) * 4096 + h * 64 + w] = fmaxf(acc[r], 0.f);
        }
    }
}

extern "C" void kernel_launch(void* const* d_in, const int* in_sizes, int n_in,
                              void* d_out, int out_size, void* d_ws, size_t ws_size,
                              hipStream_t stream) {
    const float* buf = (const float*)d_in[0];
    const float* Wq  = (const float*)d_in[1];
    const float* Wk  = (const float*)d_in[2];
    const float* Wv  = (const float*)d_in[3];
    const float* Wc  = (const float*)d_in[4];
    const float* W1  = (const float*)d_in[5];
    const float* W2  = (const float*)d_in[6];
    float* ws  = (float*)d_ws;
    float* out = (float*)d_out;

    prep_weights<<<208, 256, 0, stream>>>(Wq, Wk, Wv, Wc, W1, W2, ws);
    proj_kernel<<<2560, 256, 0, stream>>>(buf, ws);
    attn_conv<<<512, 512, 0, stream>>>(ws, out);
}